// Round 2
// baseline (3985.480 us; speedup 1.0000x reference)
//
#include <hip/hip_runtime.h>
#include <cstdint>
#include <cstddef>

typedef unsigned short u16;
typedef unsigned int u32;
typedef unsigned long long u64;
typedef __attribute__((ext_vector_type(8))) short short8;   // 8 x bf16
typedef __attribute__((ext_vector_type(4))) float f32x4;

#define MFMA16(a, b, c) __builtin_amdgcn_mfma_f32_16x16x32_bf16((a), (b), (c), 0, 0, 0)
#define SCOPE_AGENT __HIP_MEMORY_SCOPE_AGENT

// B=64, T=512, D=512, H=1024.
// hi/lo bf16 split everywhere: fp32-grade via 3 MFMA products (round-1 absmax 0.0039).
// R2: h stored as SEPARATE hi/lo bf16 planes (load IS the short8 frag, zero unpack);
//     poll loads issued before any store (vmcnt issue-order fix); per-chunk __all()
//     freshness -> compute fresh chunks while stale chunk reloads are in flight.

static __device__ __forceinline__ u16 f2bf_rne(float f) {
  uint32_t u = __float_as_uint(f);
  u += 0x7FFFu + ((u >> 16) & 1u);
  return (u16)(u >> 16);
}
static __device__ __forceinline__ float bf2f(u16 h) {
  return __uint_as_float((uint32_t)h << 16);
}
// sentinel: 0xFFFFFFFF = two bf16 NaNs; tanh output / its bf16 remainder are always
// finite -> never NaN -> sentinel unambiguous. Each u32 is one producer-thread store.
static __device__ __forceinline__ bool fresh2(u64 d) {
  return ((u32)d != 0xFFFFFFFFu) && ((u32)(d >> 32) != 0xFFFFFFFFu);
}

// ---------------- prep ----------------
__global__ void split_arr(const float* __restrict__ src, u16* __restrict__ hi,
                          u16* __restrict__ lo, int n) {
  int i = blockIdx.x * blockDim.x + threadIdx.x;
  if (i >= n) return;
  float f = src[i];
  u16 h = f2bf_rne(f);
  hi[i] = h;
  lo[i] = f2bf_rne(f - bf2f(h));
}

__global__ void bias_init(const float* __restrict__ a, const float* __restrict__ b,
                          float* __restrict__ o, u32* __restrict__ cnt) {
  int i = blockIdx.x * blockDim.x + threadIdx.x;
  if (i < 1024) o[i] = a[i] + b[i];
  if (i < 4)  // startup-barrier counter per batch-group (256B padded)
    __hip_atomic_store(cnt + i * 64, 0u, __ATOMIC_RELAXED, SCOPE_AGENT);
}

// ---------------- phase 1: xin = x @ W_in^T + bsum -> d_out (unchanged, proven) ----
__global__ __launch_bounds__(256) void xin_gemm(
    const float* __restrict__ x, const u16* __restrict__ Bh, const u16* __restrict__ Bl,
    const float* __restrict__ bsum, float* __restrict__ out) {
  __shared__ u16 Ahi[64 * 40], Alo[64 * 40], Bhi[64 * 40], Blo[64 * 40];
  const int mb = blockIdx.y * 64, nb = blockIdx.x * 64;
  const int tid = threadIdx.x, wave = tid >> 6, lane = tid & 63;
  const int mn = lane & 15, q = lane >> 4;
  const int srow = tid >> 2, scg = tid & 3;

  f32x4 acc[4] = {};
  for (int kb = 0; kb < 512; kb += 32) {
    const float* ap = x + (size_t)(mb + srow) * 512 + kb + scg * 8;
    float4 a0 = *(const float4*)ap;
    float4 a1 = *(const float4*)(ap + 4);
    float av[8] = {a0.x, a0.y, a0.z, a0.w, a1.x, a1.y, a1.z, a1.w};
    short8 vh, vl;
#pragma unroll
    for (int j = 0; j < 8; ++j) {
      u16 h = f2bf_rne(av[j]);
      vh[j] = (short)h;
      vl[j] = (short)f2bf_rne(av[j] - bf2f(h));
    }
    short8 wh = *(const short8*)(Bh + (size_t)(nb + srow) * 512 + kb + scg * 8);
    short8 wl = *(const short8*)(Bl + (size_t)(nb + srow) * 512 + kb + scg * 8);

    __syncthreads();
    *(short8*)&Ahi[srow * 40 + scg * 8] = vh;
    *(short8*)&Alo[srow * 40 + scg * 8] = vl;
    *(short8*)&Bhi[srow * 40 + scg * 8] = wh;
    *(short8*)&Blo[srow * 40 + scg * 8] = wl;
    __syncthreads();

    short8 ah = *(const short8*)&Ahi[(wave * 16 + mn) * 40 + q * 8];
    short8 al = *(const short8*)&Alo[(wave * 16 + mn) * 40 + q * 8];
#pragma unroll
    for (int nt = 0; nt < 4; ++nt) {
      short8 bh8 = *(const short8*)&Bhi[(nt * 16 + mn) * 40 + q * 8];
      short8 bl8 = *(const short8*)&Blo[(nt * 16 + mn) * 40 + q * 8];
      acc[nt] = MFMA16(ah, bh8, acc[nt]);
      acc[nt] = MFMA16(al, bh8, acc[nt]);
      acc[nt] = MFMA16(ah, bl8, acc[nt]);
    }
  }
#pragma unroll
  for (int nt = 0; nt < 4; ++nt)
#pragma unroll
    for (int r = 0; r < 4; ++r) {
      int row = mb + wave * 16 + q * 4 + r;
      int col = nb + nt * 16 + mn;
      out[(size_t)row * 1024 + col] = acc[nt][r] + bsum[col];
    }
}

// ---------------- phase 2: recurrence ----------------
// grid (32,4): cg -> 32-col tile (W rows c0..c0+31 persistent in LDS, hi+lo),
// bg -> 16-batch group. h as two bf16 planes [4 bufs][64][1024]; buf[t&3] = h_t.
// Per step: [issue 32 poll u64 loads FIRST] [xin prefetch] [per-chunk: __all-fresh ->
// ds_read W + MFMA, else reload] [LDS reduce, 1 sync] [reset buf[(t+2)&3]] [tanh]
// [vmcnt(0) drains resets] [store h_(t+1) hi/lo] [store out].
__global__ __launch_bounds__(256, 1) void rnn_steps(
    const u16* __restrict__ Wh, const u16* __restrict__ Wl, u16* hhi, u16* hlo,
    u32* cnt, float* __restrict__ io) {
  extern __shared__ __align__(16) char smem[];
  u16* Whi = (u16*)smem;                        // [32][1032]  66048 B
  u16* Wlo = (u16*)(smem + 66048);              // [32][1032]  66048 B
  float* red = (float*)(smem + 132096);         // [2][4][16][33] 16896 B

  const int tid = threadIdx.x, wave = tid >> 6, lane = tid & 63;
  const int mn = lane & 15, q = lane >> 4;
  const int cg = blockIdx.x, bg = blockIdx.y;
  const int c0 = cg * 32, b0 = bg * 16;
  u32* mycnt = cnt + bg * 64;

  // persistent W tile: 32 rows x 1024, hi+lo
  for (int it = tid; it < 32 * 128; it += 256) {
    int r = it >> 7, c = it & 127;
    *(short8*)&Whi[r * 1032 + c * 8] = *(const short8*)(Wh + (size_t)(c0 + r) * 1024 + c * 8);
    *(short8*)&Wlo[r * 1032 + c * 8] = *(const short8*)(Wl + (size_t)(c0 + r) * 1024 + c * 8);
  }

  // output ownership: 256 threads -> 16 batches x 32 cols, 2 cols/thread
  const int om = tid >> 4, on2 = (tid & 15) * 2;
  const u32 hw = (u32)(b0 + om) * 512 + (u32)(c0 + on2) / 2;  // u32 index in a plane

  // sentinel-prefill my words of buffers 1..3 (buf0's first poll is t=4, covered by
  // the in-loop reset at t=2); one startup barrier publishes before any poll.
#pragma unroll
  for (int bb = 1; bb < 4; ++bb) {
    __hip_atomic_store((u32*)hhi + ((size_t)bb << 15) + hw, 0xFFFFFFFFu, __ATOMIC_RELAXED,
                       SCOPE_AGENT);
    __hip_atomic_store((u32*)hlo + ((size_t)bb << 15) + hw, 0xFFFFFFFFu, __ATOMIC_RELAXED,
                       SCOPE_AGENT);
  }
  asm volatile("s_waitcnt vmcnt(0)" ::: "memory");
  __syncthreads();
  if (tid == 0) {
    __hip_atomic_fetch_add(mycnt, 1u, __ATOMIC_RELAXED, SCOPE_AGENT);
    while (__hip_atomic_load(mycnt, __ATOMIC_RELAXED, SCOPE_AGENT) < 32u)
      __builtin_amdgcn_s_sleep(1);
  }
  __syncthreads();

  const size_t iobase = ((size_t)(b0 + om) * 512) * 1024 + c0 + on2;
  float2 xv = *(const float2*)(io + iobase);  // xin(0)

  // ---- t = 0: h0 == 0 -> h1 = tanh(xin0), no GEMM ----
  {
    float2 xn = *(const float2*)(io + iobase + 1024);  // xin(1)
    float o0 = tanhf(xv.x), o1 = tanhf(xv.y);
    u16 h0 = f2bf_rne(o0), h1 = f2bf_rne(o1);
    u16 l0 = f2bf_rne(o0 - bf2f(h0)), l1 = f2bf_rne(o1 - bf2f(h1));
    __hip_atomic_store((u32*)hhi + ((size_t)1 << 15) + hw, (u32)h0 | ((u32)h1 << 16),
                       __ATOMIC_RELAXED, SCOPE_AGENT);
    __hip_atomic_store((u32*)hlo + ((size_t)1 << 15) + hw, (u32)l0 | ((u32)l1 << 16),
                       __ATOMIC_RELAXED, SCOPE_AGENT);
    *(float2*)(io + iobase) = make_float2(o0, o1);
    xv = xn;
  }

  const int kbase = wave * 256;
  for (int t = 1; t < 512; ++t) {
    const u16* ch = hhi + ((size_t)(t & 3) << 16);
    const u16* cl = hlo + ((size_t)(t & 3) << 16);
    // A-row pointers: row b0+mn, features kbase + q*8 (+ kt*32 per chunk)
    const u64* ph = (const u64*)(ch + (size_t)(b0 + mn) * 1024 + kbase) + q * 2;
    const u64* pl = (const u64*)(cl + (size_t)(b0 + mn) * 1024 + kbase) + q * 2;

    // ---- issue ALL poll loads first (nothing else ahead of them in vmcnt order) ----
    u64 vh[8][2], vl[8][2];
#pragma unroll
    for (int kt = 0; kt < 8; ++kt) {
      vh[kt][0] = __hip_atomic_load(ph + kt * 8 + 0, __ATOMIC_RELAXED, SCOPE_AGENT);
      vh[kt][1] = __hip_atomic_load(ph + kt * 8 + 1, __ATOMIC_RELAXED, SCOPE_AGENT);
      vl[kt][0] = __hip_atomic_load(pl + kt * 8 + 0, __ATOMIC_RELAXED, SCOPE_AGENT);
      vl[kt][1] = __hip_atomic_load(pl + kt * 8 + 1, __ATOMIC_RELAXED, SCOPE_AGENT);
    }
    float2 xv_next;
    if (t < 511) xv_next = *(const float2*)(io + iobase + (size_t)(t + 1) * 1024);

    // ---- per-chunk: compute when wave-uniformly fresh; reload stale; repeat ----
    f32x4 acc[2] = {};
    u32 done = 0;
    while (done != 0xFFu) {
#pragma unroll
      for (int kt = 0; kt < 8; ++kt) {
        if (done & (1u << kt)) continue;
        bool f = fresh2(vh[kt][0]) && fresh2(vh[kt][1]) && fresh2(vl[kt][0]) &&
                 fresh2(vl[kt][1]);
        if (__all(f)) {
          const int k = kbase + kt * 32 + q * 8;
          union { u64 d[2]; short8 s; } Uh, Ul;
          Uh.d[0] = vh[kt][0]; Uh.d[1] = vh[kt][1];
          Ul.d[0] = vl[kt][0]; Ul.d[1] = vl[kt][1];
#pragma unroll
          for (int nt = 0; nt < 2; ++nt) {
            short8 bh = *(const short8*)&Whi[(nt * 16 + mn) * 1032 + k];
            short8 bl = *(const short8*)&Wlo[(nt * 16 + mn) * 1032 + k];
            acc[nt] = MFMA16(Uh.s, bh, acc[nt]);
            acc[nt] = MFMA16(Ul.s, bh, acc[nt]);
            acc[nt] = MFMA16(Uh.s, bl, acc[nt]);
          }
          done |= 1u << kt;
        } else {
          vh[kt][0] = __hip_atomic_load(ph + kt * 8 + 0, __ATOMIC_RELAXED, SCOPE_AGENT);
          vh[kt][1] = __hip_atomic_load(ph + kt * 8 + 1, __ATOMIC_RELAXED, SCOPE_AGENT);
          vl[kt][0] = __hip_atomic_load(pl + kt * 8 + 0, __ATOMIC_RELAXED, SCOPE_AGENT);
          vl[kt][1] = __hip_atomic_load(pl + kt * 8 + 1, __ATOMIC_RELAXED, SCOPE_AGENT);
        }
      }
    }

    // ---- cross-wave K-reduction (double-buffered red, 1 syncthreads/step) ----
    float* rp = red + (t & 1) * 2112;
#pragma unroll
    for (int nt = 0; nt < 2; ++nt)
#pragma unroll
      for (int r = 0; r < 4; ++r)
        rp[wave * 528 + (q * 4 + r) * 33 + nt * 16 + mn] = acc[nt][r];
    __syncthreads();

    // reset buf[(t+2)&3] now (old content h(t-2) provably fully consumed);
    // completion overlaps the sum+tanh below, drained by vmcnt(0) before h store.
    if (t < 510) {
      __hip_atomic_store((u32*)hhi + (((size_t)(t + 2) & 3) << 15) + hw, 0xFFFFFFFFu,
                         __ATOMIC_RELAXED, SCOPE_AGENT);
      __hip_atomic_store((u32*)hlo + (((size_t)(t + 2) & 3) << 15) + hw, 0xFFFFFFFFu,
                         __ATOMIC_RELAXED, SCOPE_AGENT);
    }

    float s0 = 0.f, s1 = 0.f;
#pragma unroll
    for (int w = 0; w < 4; ++w) {
      s0 += rp[w * 528 + om * 33 + on2];
      s1 += rp[w * 528 + om * 33 + on2 + 1];
    }
    float o0 = tanhf(s0 + xv.x);
    float o1 = tanhf(s1 + xv.y);

    if (t < 511) {
      u16 h0 = f2bf_rne(o0), h1 = f2bf_rne(o1);
      u16 l0 = f2bf_rne(o0 - bf2f(h0)), l1 = f2bf_rne(o1 - bf2f(h1));
      // drain resets so sentinel cannot land after the data stores below
      asm volatile("s_waitcnt vmcnt(0)" ::: "memory");
      __hip_atomic_store((u32*)hhi + (((size_t)(t + 1) & 3) << 15) + hw,
                         (u32)h0 | ((u32)h1 << 16), __ATOMIC_RELAXED, SCOPE_AGENT);
      __hip_atomic_store((u32*)hlo + (((size_t)(t + 1) & 3) << 15) + hw,
                         (u32)l0 | ((u32)l1 << 16), __ATOMIC_RELAXED, SCOPE_AGENT);
    }
    *(float2*)(io + iobase + (size_t)t * 1024) = make_float2(o0, o1);
    xv = xv_next;
  }
}

// ---------------- host ----------------
extern "C" void kernel_launch(void* const* d_in, const int* in_sizes, int n_in, void* d_out,
                              int out_size, void* d_ws, size_t ws_size, hipStream_t stream) {
  (void)in_sizes; (void)n_in; (void)out_size; (void)ws_size;
  const float* x    = (const float*)d_in[0];
  const float* W_in = (const float*)d_in[1];
  const float* b_in = (const float*)d_in[2];
  const float* W_hh = (const float*)d_in[3];
  const float* bias = (const float*)d_in[4];
  float* out = (float*)d_out;
  char* ws = (char*)d_ws;

  u16* win_hi = (u16*)(ws);
  u16* win_lo = (u16*)(ws + (1u << 20));
  u16* whh_hi = (u16*)(ws + (2u << 20));
  u16* whh_lo = (u16*)(ws + (4u << 20));
  float* bsum = (float*)(ws + (6u << 20));
  u16* hhi    = (u16*)(ws + (6u << 20) + 65536);               // 4 x 64x1024 u16 = 512 KB
  u16* hlo    = (u16*)(ws + (6u << 20) + 65536 + (512u << 10)); // 512 KB
  u32* cnt    = (u32*)(ws + (6u << 20) + 65536 + (1u << 20));  // 4 x 256B padded counters

  split_arr<<<dim3(524288 / 256), dim3(256), 0, stream>>>(W_in, win_hi, win_lo, 524288);
  split_arr<<<dim3(1048576 / 256), dim3(256), 0, stream>>>(W_hh, whh_hi, whh_lo, 1048576);
  bias_init<<<dim3(4), dim3(256), 0, stream>>>(b_in, bias, bsum, cnt);

  xin_gemm<<<dim3(16, 512), dim3(256), 0, stream>>>(x, win_hi, win_lo, bsum, out);

  static const unsigned kSmem = 148992;  // 2*66048 + 16896
  hipFuncSetAttribute((const void*)rnn_steps, hipFuncAttributeMaxDynamicSharedMemorySize,
                      (int)kSmem);
  void* args[6];
  args[0] = (void*)&whh_hi;
  args[1] = (void*)&whh_lo;
  args[2] = (void*)&hhi;
  args[3] = (void*)&hlo;
  args[4] = (void*)&cnt;
  args[5] = (void*)&out;
  hipLaunchCooperativeKernel((const void*)rnn_steps, dim3(32, 4), dim3(256, 1, 1), args, kSmem,
                             stream);
}

// Round 5
// 3713.973 us; speedup vs baseline: 1.0731x; 1.0731x over previous
//
#include <hip/hip_runtime.h>
#include <cstdint>
#include <cstddef>

typedef unsigned short u16;
typedef unsigned int u32;
typedef unsigned long long u64;
typedef __attribute__((ext_vector_type(8))) short short8;   // 8 x bf16
typedef __attribute__((ext_vector_type(4))) float f32x4;

#define MFMA16(a, b, c) __builtin_amdgcn_mfma_f32_16x16x32_bf16((a), (b), (c), 0, 0, 0)
#define SCOPE_AGENT __HIP_MEMORY_SCOPE_AGENT

// B=64, T=512, D=512, H=1024.
// R5: XCD-local h exchange, hang-proof. 8 bgs x 32 cgs = 256 WGs, bg = blockIdx&7
// (round-robin dispatch -> one XCD per bg, runtime-checked via hwreg XCC_ID).
// ALL h stores are agent-scope (proven R0-R2 visibility; they also update the
// producer's XCD L2 en route to MALL). Polls: sc0 (XCD L2) when verified, with a
// bounded spin (256 rounds) + sticky per-lane escalation to agent loads -> spin
// termination rests only on the proven agent/agent pair, never on topology.
// Depth-8 h rotation, reset-ahead-4 (reset(t)->buf[(t+4)&7] drained by t+1's
// vmcnt(0), data store at t+3, poll at t+4). A-frag folds hi/lo (rows 0-7 = h_hi
// of 8 batches, rows 8-15 = h_lo) -> 2 MFMA/chunk incl. free lo*lo term; W frags
// hoisted to VGPRs (1 WG/CU).

static __device__ __forceinline__ u16 f2bf_rne(float f) {
  uint32_t u = __float_as_uint(f);
  u += 0x7FFFu + ((u >> 16) & 1u);
  return (u16)(u >> 16);
}
static __device__ __forceinline__ float bf2f(u16 h) {
  return __uint_as_float((uint32_t)h << 16);
}

// sentinel 0xFFFF = bf16 NaN; tanh outputs / remainders are finite -> never 0xFFFF.
static __device__ __forceinline__ u32 stale4(int4 d) {
  u32 s = 0;
#pragma unroll
  for (int j = 0; j < 4; ++j) {
    u32 x = ((u32*)&d)[j];
    s |= (u32)((x >> 16) == 0xFFFFu) | (u32)((x & 0xFFFFu) == 0xFFFFu);
  }
  return s;
}

// fast: sc0 load (XCD L2). esc: agent-scope atomic loads (proven-visible pair).
static __device__ __forceinline__ int4 ld16(const u16* p, bool esc) {
  int4 r;
  if (!esc) {
    asm volatile("global_load_dwordx4 %0, %1, off sc0" : "=v"(r) : "v"(p));
  } else {
    u64 a = __hip_atomic_load((const u64*)p, __ATOMIC_RELAXED, SCOPE_AGENT);
    u64 b = __hip_atomic_load(((const u64*)p) + 1, __ATOMIC_RELAXED, SCOPE_AGENT);
    r.x = (int)(u32)a; r.y = (int)(u32)(a >> 32);
    r.z = (int)(u32)b; r.w = (int)(u32)(b >> 32);
  }
  return r;
}
static __device__ __forceinline__ void stH(u16* p, u32 v) {
  __hip_atomic_store(p, (u16)v, __ATOMIC_RELAXED, SCOPE_AGENT);
}

// rule #18: drain vmcnt, then hard scheduling fence so no dependent reg-only op
// (stale checks / MFMA) is hoisted above the wait by the machine scheduler.
static __device__ __forceinline__ void waitv0() {
  asm volatile("s_waitcnt vmcnt(0)" ::: "memory");
  __builtin_amdgcn_sched_barrier(0);
}

// ---------------- prep ----------------
__global__ void split_arr(const float* __restrict__ src, u16* __restrict__ hi,
                          u16* __restrict__ lo, int n) {
  int i = blockIdx.x * blockDim.x + threadIdx.x;
  if (i >= n) return;
  float f = src[i];
  u16 h = f2bf_rne(f);
  hi[i] = h;
  lo[i] = f2bf_rne(f - bf2f(h));
}

__global__ void bias_init(const float* __restrict__ a, const float* __restrict__ b,
                          float* __restrict__ o, u32* __restrict__ cnt) {
  int i = blockIdx.x * blockDim.x + threadIdx.x;
  if (i < 1024) o[i] = a[i] + b[i];
  if (i < 8)  // per-bg startup counters (256B padded)
    __hip_atomic_store(cnt + i * 64, 0u, __ATOMIC_RELAXED, SCOPE_AGENT);
}

// ---------------- phase 1: xin = x @ W_in^T + bsum -> d_out (unchanged, proven) ----
__global__ __launch_bounds__(256) void xin_gemm(
    const float* __restrict__ x, const u16* __restrict__ Bh, const u16* __restrict__ Bl,
    const float* __restrict__ bsum, float* __restrict__ out) {
  __shared__ u16 Ahi[64 * 40], Alo[64 * 40], Bhi[64 * 40], Blo[64 * 40];
  const int mb = blockIdx.y * 64, nb = blockIdx.x * 64;
  const int tid = threadIdx.x, wave = tid >> 6, lane = tid & 63;
  const int mn = lane & 15, q = lane >> 4;
  const int srow = tid >> 2, scg = tid & 3;

  f32x4 acc[4] = {};
  for (int kb = 0; kb < 512; kb += 32) {
    const float* ap = x + (size_t)(mb + srow) * 512 + kb + scg * 8;
    float4 a0 = *(const float4*)ap;
    float4 a1 = *(const float4*)(ap + 4);
    float av[8] = {a0.x, a0.y, a0.z, a0.w, a1.x, a1.y, a1.z, a1.w};
    short8 vh, vl;
#pragma unroll
    for (int j = 0; j < 8; ++j) {
      u16 h = f2bf_rne(av[j]);
      vh[j] = (short)h;
      vl[j] = (short)f2bf_rne(av[j] - bf2f(h));
    }
    short8 wh = *(const short8*)(Bh + (size_t)(nb + srow) * 512 + kb + scg * 8);
    short8 wl = *(const short8*)(Bl + (size_t)(nb + srow) * 512 + kb + scg * 8);

    __syncthreads();
    *(short8*)&Ahi[srow * 40 + scg * 8] = vh;
    *(short8*)&Alo[srow * 40 + scg * 8] = vl;
    *(short8*)&Bhi[srow * 40 + scg * 8] = wh;
    *(short8*)&Blo[srow * 40 + scg * 8] = wl;
    __syncthreads();

    short8 ah = *(const short8*)&Ahi[(wave * 16 + mn) * 40 + q * 8];
    short8 al = *(const short8*)&Alo[(wave * 16 + mn) * 40 + q * 8];
#pragma unroll
    for (int nt = 0; nt < 4; ++nt) {
      short8 bh8 = *(const short8*)&Bhi[(nt * 16 + mn) * 40 + q * 8];
      short8 bl8 = *(const short8*)&Blo[(nt * 16 + mn) * 40 + q * 8];
      acc[nt] = MFMA16(ah, bh8, acc[nt]);
      acc[nt] = MFMA16(al, bh8, acc[nt]);
      acc[nt] = MFMA16(ah, bl8, acc[nt]);
    }
  }
#pragma unroll
  for (int nt = 0; nt < 4; ++nt)
#pragma unroll
    for (int r = 0; r < 4; ++r) {
      int row = mb + wave * 16 + q * 4 + r;
      int col = nb + nt * 16 + mn;
      out[(size_t)row * 1024 + col] = acc[nt][r] + bsum[col];
    }
}

// ---------------- phase 2 step loop ----------------
// Per step t: [issue 8 poll loads] [vmcnt(0)+sched_barrier — also drains prev-step
// reset/h/io stores] [bounded retry, sticky escalation] [xin prefetch] [reset
// buf[(t+4)&7]] [8x2x2 MFMA, W in regs] [red write, 1 sync] [sum hi-row + lo-row
// over 4 waves] [tanh] [h store buf[(t+1)&7]] [io store]. Same-address order
// (reset(t) -> data h(t+4) at step t+3) enforced by step-t+1's vmcnt(0); skew
// across WGs <= 1 step (full data dependency each step).
static __device__ __forceinline__ void run_steps(
    u16* hhi, u16* hlo, float* __restrict__ io, const u16* Whi, const u16* Wlo,
    float* red, int b0, int c0, int wave, int mn, int q, int om, int on, bool esc) {
  const int kbase = wave * 256;
  u16* aplane = (mn < 8) ? hhi : hlo;  // A rows 0-7 = hi, 8-15 = lo
  const size_t abase = (size_t)(b0 + (mn & 7)) * 1024 + kbase + q * 8;
  const size_t iobase = (size_t)(b0 + om) * 512 * 1024 + (c0 + on);
  const size_t hword = (size_t)(b0 + om) * 1024 + (c0 + on);

  // hoist W frags to registers (1 WG/CU -> 1 wave/SIMD -> ~512 VGPR budget)
  short8 bhf[8][2], blf[8][2];
#pragma unroll
  for (int kt = 0; kt < 8; ++kt) {
    const int k = kbase + kt * 32 + q * 8;
#pragma unroll
    for (int nt = 0; nt < 2; ++nt) {
      bhf[kt][nt] = *(const short8*)&Whi[(nt * 16 + mn) * 1032 + k];
      blf[kt][nt] = *(const short8*)&Wlo[(nt * 16 + mn) * 1032 + k];
    }
  }

  float xv = io[iobase];  // xin(0)
  {                       // t = 0: h0 == 0 -> h1 = tanh(xin0), no GEMM
    float xn = io[iobase + 1024];
    float o = tanhf(xv);
    u16 hh = f2bf_rne(o);
    stH(hhi + (1u << 16) + hword, hh);
    stH(hlo + (1u << 16) + hword, f2bf_rne(o - bf2f(hh)));
    io[iobase] = o;
    xv = xn;
  }

  for (int t = 1; t < 512; ++t) {
    const u16* pA = aplane + ((size_t)(t & 7) << 16) + abase;
    int4 v[8];
#pragma unroll
    for (int kt = 0; kt < 8; ++kt) v[kt] = ld16(pA + kt * 32, esc);
    waitv0();
    u32 sm = 0;
#pragma unroll
    for (int kt = 0; kt < 8; ++kt) sm |= stale4(v[kt]) << kt;
    int spins = 0;
    while (sm) {
      if (!esc && ++spins >= 256) esc = true;  // sticky: proven-visible pair forever
#pragma unroll
      for (int kt = 0; kt < 8; ++kt)
        if (sm & (1u << kt)) v[kt] = ld16(pA + kt * 32, esc);
      waitv0();
      sm = 0;
#pragma unroll
      for (int kt = 0; kt < 8; ++kt) sm |= stale4(v[kt]) << kt;
    }

    float xn = 0.f;
    if (t < 511) xn = io[iobase + (size_t)(t + 1) * 1024];
    if (t < 508) {  // reset buf[(t+4)&7]: holds h(t-4), consumed >=4 steps ago
      const size_t roff = ((size_t)((t + 4) & 7) << 16) + hword;
      stH(hhi + roff, 0xFFFFu);
      stH(hlo + roff, 0xFFFFu);
    }

    f32x4 acc[2] = {};
#pragma unroll
    for (int kt = 0; kt < 8; ++kt) {
      short8 a = *(short8*)&v[kt];
#pragma unroll
      for (int nt = 0; nt < 2; ++nt) {
        acc[nt] = MFMA16(a, bhf[kt][nt], acc[nt]);  // rows 0-7: hi*Whi, 8-15: lo*Whi
        acc[nt] = MFMA16(a, blf[kt][nt], acc[nt]);  // rows 0-7: hi*Wlo, 8-15: lo*Wlo
      }
    }

    float* rp = red + (t & 1) * 2112;
#pragma unroll
    for (int nt = 0; nt < 2; ++nt)
#pragma unroll
      for (int r = 0; r < 4; ++r)
        rp[wave * 528 + (q * 4 + r) * 33 + nt * 16 + mn] = acc[nt][r];
    __syncthreads();

    float s = 0.f;
#pragma unroll
    for (int w = 0; w < 4; ++w)
      s += rp[w * 528 + om * 33 + on] + rp[w * 528 + (om + 8) * 33 + on];
    float o = tanhf(s + xv);

    if (t < 511) {
      u16 hh = f2bf_rne(o);
      const size_t doff = ((size_t)((t + 1) & 7) << 16) + hword;
      stH(hhi + doff, hh);
      stH(hlo + doff, f2bf_rne(o - bf2f(hh)));
    }
    io[iobase + (size_t)t * 1024] = o;
    xv = xn;
  }
}

// ---------------- phase 2 kernel ----------------
__global__ __launch_bounds__(256, 1) void rnn_steps(
    const u16* __restrict__ Wh, const u16* __restrict__ Wl, u16* hhi, u16* hlo,
    u32* cnt, u32* xccbuf, float* __restrict__ io) {
  extern __shared__ __align__(16) char smem[];
  u16* Whi = (u16*)smem;                 // [32][1032]  66048 B
  u16* Wlo = (u16*)(smem + 66048);       // [32][1032]  66048 B
  float* red = (float*)(smem + 132096);  // [2][4][16][33] 16896 B

  const int tid = threadIdx.x, wave = tid >> 6, lane = tid & 63;
  const int mn = lane & 15, q = lane >> 4;
  const int wgid = blockIdx.x;
  const int bg = wgid & 7, cg = wgid >> 3;
  const int c0 = cg * 32, b0 = bg * 8;
  u32* mycnt = cnt + bg * 64;

  // persistent W tile: 32 cols x 1024, hi+lo
  for (int it = tid; it < 32 * 128; it += 256) {
    int r = it >> 7, c = it & 127;
    *(short8*)&Whi[r * 1032 + c * 8] = *(const short8*)(Wh + (size_t)(c0 + r) * 1024 + c * 8);
    *(short8*)&Wlo[r * 1032 + c * 8] = *(const short8*)(Wl + (size_t)(c0 + r) * 1024 + c * 8);
  }

  // output ownership: 256 threads -> 8 batches x 32 cols, 1 col/thread
  const int om = tid >> 5, on = tid & 31;
  const size_t hword = (size_t)(b0 + om) * 1024 + (c0 + on);

  // sentinel-prefill my word in ALL 8 buffers (agent scope: MALL + local L2 both see
  // it; t=0's buf1 data store is ordered after via the pre-barrier vmcnt drain)
#pragma unroll
  for (int bb = 0; bb < 8; ++bb) {
    stH(hhi + ((size_t)bb << 16) + hword, 0xFFFFu);
    stH(hlo + ((size_t)bb << 16) + hword, 0xFFFFu);
  }

  // publish my XCD id (numeric hwreg 20 = XCC_ID on gfx94x/950, low 4 bits);
  // per-bg startup barrier; then verify bg co-residency. Wrong id/garbage is safe:
  // false-negative -> slow path; false-positive -> bounded-spin escalation.
  u32 xcc;
  asm volatile("s_getreg_b32 %0, hwreg(20, 0, 4)" : "=s"(xcc));
  if (tid == 0)
    __hip_atomic_store(xccbuf + wgid, xcc, __ATOMIC_RELAXED, SCOPE_AGENT);
  asm volatile("s_waitcnt vmcnt(0)" ::: "memory");
  __syncthreads();
  if (tid == 0) {
    __hip_atomic_fetch_add(mycnt, 1u, __ATOMIC_RELAXED, SCOPE_AGENT);
    while (__hip_atomic_load(mycnt, __ATOMIC_RELAXED, SCOPE_AGENT) < 32u)
      __builtin_amdgcn_s_sleep(1);
  }
  __syncthreads();

  u32 pv = __hip_atomic_load(xccbuf + bg + 8 * (lane & 31), __ATOMIC_RELAXED, SCOPE_AGENT);
  const bool fast = (__ballot(pv == xcc) == ~0ull);

  run_steps(hhi, hlo, io, Whi, Wlo, red, b0, c0, wave, mn, q, om, on, !fast);
}

// ---------------- host ----------------
extern "C" void kernel_launch(void* const* d_in, const int* in_sizes, int n_in, void* d_out,
                              int out_size, void* d_ws, size_t ws_size, hipStream_t stream) {
  (void)in_sizes; (void)n_in; (void)out_size; (void)ws_size;
  const float* x    = (const float*)d_in[0];
  const float* W_in = (const float*)d_in[1];
  const float* b_in = (const float*)d_in[2];
  const float* W_hh = (const float*)d_in[3];
  const float* bias = (const float*)d_in[4];
  float* out = (float*)d_out;
  char* ws = (char*)d_ws;

  u16* win_hi = (u16*)(ws);                     // 1 MB, dead after xin_gemm
  u16* win_lo = (u16*)(ws + (1u << 20));        // 1 MB, dead after xin_gemm
  u16* whh_hi = (u16*)(ws + (2u << 20));        // 2 MB
  u16* whh_lo = (u16*)(ws + (4u << 20));        // 2 MB
  float* bsum = (float*)(ws + (6u << 20));      // 4 KB
  u16* hhi    = (u16*)(ws);                     // aliases win_hi: 8 bufs x 64x1024 u16
  u16* hlo    = (u16*)(ws + (1u << 20));        // aliases win_lo
  u32* cnt    = (u32*)(ws + (6u << 20) + 65536);          // 8 x 256B counters
  u32* xcc    = (u32*)(ws + (6u << 20) + 65536 + 4096);   // 256 u32

  split_arr<<<dim3(524288 / 256), dim3(256), 0, stream>>>(W_in, win_hi, win_lo, 524288);
  split_arr<<<dim3(1048576 / 256), dim3(256), 0, stream>>>(W_hh, whh_hi, whh_lo, 1048576);
  bias_init<<<dim3(8), dim3(256), 0, stream>>>(b_in, bias, bsum, cnt);

  xin_gemm<<<dim3(16, 512), dim3(256), 0, stream>>>(x, win_hi, win_lo, bsum, out);

  static const unsigned kSmem = 148992;  // 2*66048 + 16896
  (void)hipFuncSetAttribute((const void*)rnn_steps, hipFuncAttributeMaxDynamicSharedMemorySize,
                            (int)kSmem);
  void* args[7];
  args[0] = (void*)&whh_hi;
  args[1] = (void*)&whh_lo;
  args[2] = (void*)&hhi;
  args[3] = (void*)&hlo;
  args[4] = (void*)&cnt;
  args[5] = (void*)&xcc;
  args[6] = (void*)&out;
  (void)hipLaunchCooperativeKernel((const void*)rnn_steps, dim3(256), dim3(256, 1, 1), args,
                                   kSmem, stream);
}

// Round 6
// 1977.339 us; speedup vs baseline: 2.0156x; 1.8783x over previous
//
#include <hip/hip_runtime.h>
#include <cstdint>
#include <cstddef>

typedef unsigned short u16;
typedef unsigned int u32;
typedef unsigned long long u64;
typedef __attribute__((ext_vector_type(8))) short short8;   // 8 x bf16
typedef __attribute__((ext_vector_type(4))) float f32x4;

#define MFMA16(a, b, c) __builtin_amdgcn_mfma_f32_16x16x32_bf16((a), (b), (c), 0, 0, 0)
#define SCOPE_AGENT __HIP_MEMORY_SCOPE_AGENT

// B=64, T=512, D=512, H=1024.
// R6: flag-gated XCD-local exchange. R5 proved (FETCH 593->185MB) that agent stores
// are visible to same-XCD sc0 loads and h traffic stays in L2 — but data-polling
// hammered L2 with 1MB/round/XCD of retries. Fix: per-producer MONOTONIC flags
// (flags[bg][cg] = last published step; 128B/bg). Consumers spin on the tiny flag
// block, then load the A-slice once; R5's sentinel gate + bounded-spin escalation
// to agent scope remain as the correctness/termination backstop. All stores stay
// agent-scope. Depth-8 h rotation, reset-ahead-4. A-frag folds hi/lo (rows 0-7 =
// h_hi of 8 batches, rows 8-15 = h_lo) -> 2 MFMA/chunk incl. free lo*lo term.

static __device__ __forceinline__ u16 f2bf_rne(float f) {
  uint32_t u = __float_as_uint(f);
  u += 0x7FFFu + ((u >> 16) & 1u);
  return (u16)(u >> 16);
}
static __device__ __forceinline__ float bf2f(u16 h) {
  return __uint_as_float((uint32_t)h << 16);
}

// sentinel 0xFFFF = bf16 NaN; tanh outputs / remainders are finite -> never 0xFFFF.
static __device__ __forceinline__ u32 stale4(int4 d) {
  u32 s = 0;
#pragma unroll
  for (int j = 0; j < 4; ++j) {
    u32 x = ((u32*)&d)[j];
    s |= (u32)((x >> 16) == 0xFFFFu) | (u32)((x & 0xFFFFu) == 0xFFFFu);
  }
  return s;
}

// fast: sc0 load (XCD L2). esc: agent-scope atomic loads (proven-visible pair).
static __device__ __forceinline__ int4 ld16(const u16* p, bool esc) {
  int4 r;
  if (!esc) {
    asm volatile("global_load_dwordx4 %0, %1, off sc0" : "=v"(r) : "v"(p));
  } else {
    u64 a = __hip_atomic_load((const u64*)p, __ATOMIC_RELAXED, SCOPE_AGENT);
    u64 b = __hip_atomic_load(((const u64*)p) + 1, __ATOMIC_RELAXED, SCOPE_AGENT);
    r.x = (int)(u32)a; r.y = (int)(u32)(a >> 32);
    r.z = (int)(u32)b; r.w = (int)(u32)(b >> 32);
  }
  return r;
}
static __device__ __forceinline__ u32 ldF(const u32* p, bool esc) {
  u32 r;
  if (!esc)
    asm volatile("global_load_dword %0, %1, off sc0" : "=v"(r) : "v"(p));
  else
    r = __hip_atomic_load(p, __ATOMIC_RELAXED, SCOPE_AGENT);
  return r;
}
static __device__ __forceinline__ void stH(u16* p, u32 v) {
  __hip_atomic_store(p, (u16)v, __ATOMIC_RELAXED, SCOPE_AGENT);
}
static __device__ __forceinline__ void stF(u32* p, u32 v) {
  __hip_atomic_store(p, v, __ATOMIC_RELAXED, SCOPE_AGENT);
}

// rule #18: drain vmcnt, then hard scheduling fence.
static __device__ __forceinline__ void waitv0() {
  asm volatile("s_waitcnt vmcnt(0)" ::: "memory");
  __builtin_amdgcn_sched_barrier(0);
}

// ---------------- prep ----------------
__global__ void split_arr(const float* __restrict__ src, u16* __restrict__ hi,
                          u16* __restrict__ lo, int n) {
  int i = blockIdx.x * blockDim.x + threadIdx.x;
  if (i >= n) return;
  float f = src[i];
  u16 h = f2bf_rne(f);
  hi[i] = h;
  lo[i] = f2bf_rne(f - bf2f(h));
}

__global__ void bias_init(const float* __restrict__ a, const float* __restrict__ b,
                          float* __restrict__ o, u32* __restrict__ cnt,
                          u32* __restrict__ flg) {
  int i = blockIdx.x * blockDim.x + threadIdx.x;
  if (i < 1024) o[i] = a[i] + b[i];
  if (i < 8)  // per-bg startup counters (256B padded)
    __hip_atomic_store(cnt + i * 64, 0u, __ATOMIC_RELAXED, SCOPE_AGENT);
  if (i < 256)  // flags[8][32] = 0 (no h published yet)
    __hip_atomic_store(flg + i, 0u, __ATOMIC_RELAXED, SCOPE_AGENT);
}

// ---------------- phase 1: xin = x @ W_in^T + bsum -> d_out (unchanged, proven) ----
__global__ __launch_bounds__(256) void xin_gemm(
    const float* __restrict__ x, const u16* __restrict__ Bh, const u16* __restrict__ Bl,
    const float* __restrict__ bsum, float* __restrict__ out) {
  __shared__ u16 Ahi[64 * 40], Alo[64 * 40], Bhi[64 * 40], Blo[64 * 40];
  const int mb = blockIdx.y * 64, nb = blockIdx.x * 64;
  const int tid = threadIdx.x, wave = tid >> 6, lane = tid & 63;
  const int mn = lane & 15, q = lane >> 4;
  const int srow = tid >> 2, scg = tid & 3;

  f32x4 acc[4] = {};
  for (int kb = 0; kb < 512; kb += 32) {
    const float* ap = x + (size_t)(mb + srow) * 512 + kb + scg * 8;
    float4 a0 = *(const float4*)ap;
    float4 a1 = *(const float4*)(ap + 4);
    float av[8] = {a0.x, a0.y, a0.z, a0.w, a1.x, a1.y, a1.z, a1.w};
    short8 vh, vl;
#pragma unroll
    for (int j = 0; j < 8; ++j) {
      u16 h = f2bf_rne(av[j]);
      vh[j] = (short)h;
      vl[j] = (short)f2bf_rne(av[j] - bf2f(h));
    }
    short8 wh = *(const short8*)(Bh + (size_t)(nb + srow) * 512 + kb + scg * 8);
    short8 wl = *(const short8*)(Bl + (size_t)(nb + srow) * 512 + kb + scg * 8);

    __syncthreads();
    *(short8*)&Ahi[srow * 40 + scg * 8] = vh;
    *(short8*)&Alo[srow * 40 + scg * 8] = vl;
    *(short8*)&Bhi[srow * 40 + scg * 8] = wh;
    *(short8*)&Blo[srow * 40 + scg * 8] = wl;
    __syncthreads();

    short8 ah = *(const short8*)&Ahi[(wave * 16 + mn) * 40 + q * 8];
    short8 al = *(const short8*)&Alo[(wave * 16 + mn) * 40 + q * 8];
#pragma unroll
    for (int nt = 0; nt < 4; ++nt) {
      short8 bh8 = *(const short8*)&Bhi[(nt * 16 + mn) * 40 + q * 8];
      short8 bl8 = *(const short8*)&Blo[(nt * 16 + mn) * 40 + q * 8];
      acc[nt] = MFMA16(ah, bh8, acc[nt]);
      acc[nt] = MFMA16(al, bh8, acc[nt]);
      acc[nt] = MFMA16(ah, bl8, acc[nt]);
    }
  }
#pragma unroll
  for (int nt = 0; nt < 4; ++nt)
#pragma unroll
    for (int r = 0; r < 4; ++r) {
      int row = mb + wave * 16 + q * 4 + r;
      int col = nb + nt * 16 + mn;
      out[(size_t)row * 1024 + col] = acc[nt][r] + bsum[col];
    }
}

// ---------------- phase 2 step loop ----------------
// Per step t: [poll 32 flags (128B) until all >= t] [issue 8 A loads, sentinel-check,
// rare retry] [xin prefetch] [reset buf[(t+4)&7]] [8x2x2 MFMA] [red write, sync]
// [cross-wave sum, tanh] [h store buf[(t+1)&7]] [sync; tid0: flag := t+1] [io store].
// Monotonic flags -> no flag ABA; data sentinel gate + bounded-spin escalation to
// agent scope -> correctness & termination never rest on topology assumptions.
static __device__ __forceinline__ void run_steps(
    u16* hhi, u16* hlo, float* __restrict__ io, const u16* Whi, const u16* Wlo,
    float* red, const u32* myflags, u32* myflag, int b0, int c0, int wave, int mn,
    int q, int om, int on, int tid, int lane, bool esc) {
  const int kbase = wave * 256;
  u16* aplane = (mn < 8) ? hhi : hlo;  // A rows 0-7 = hi, 8-15 = lo
  const size_t abase = (size_t)(b0 + (mn & 7)) * 1024 + kbase + q * 8;
  const size_t iobase = (size_t)(b0 + om) * 512 * 1024 + (c0 + on);
  const size_t hword = (size_t)(b0 + om) * 1024 + (c0 + on);
  const u32* fp = myflags + (lane & 31);  // lanes 32-63 mirror 0-31

  // W frags (compiler may keep in VGPR or re-read LDS; both fine)
  short8 bhf[8][2], blf[8][2];
#pragma unroll
  for (int kt = 0; kt < 8; ++kt) {
    const int k = kbase + kt * 32 + q * 8;
#pragma unroll
    for (int nt = 0; nt < 2; ++nt) {
      bhf[kt][nt] = *(const short8*)&Whi[(nt * 16 + mn) * 1032 + k];
      blf[kt][nt] = *(const short8*)&Wlo[(nt * 16 + mn) * 1032 + k];
    }
  }

  float xv = io[iobase];  // xin(0)
  {                       // t = 0: h0 == 0 -> h1 = tanh(xin0), no GEMM
    float xn = io[iobase + 1024];
    float o = tanhf(xv);
    u16 hh = f2bf_rne(o);
    stH(hhi + (1u << 16) + hword, hh);
    stH(hlo + (1u << 16) + hword, f2bf_rne(o - bf2f(hh)));
    __syncthreads();          // all 256 h(1) stores issued before flag
    if (tid == 0) stF(myflag, 1u);
    io[iobase] = o;
    xv = xn;
  }

  for (int t = 1; t < 512; ++t) {
    // ---- flag gate: wait until all 32 producers have published h(t) ----
    {
      int rounds = 0;
      for (;;) {
        u32 f = ldF(fp, esc);
        waitv0();  // first round also drains prev-step stores
        if (__ballot(f >= (u32)t) == ~0ull) break;
        if (!esc && ++rounds >= 256) esc = true;  // sticky, proven-visible pair
      }
    }

    // ---- A-slice load; sentinel gate (rare retries) ----
    const u16* pA = aplane + ((size_t)(t & 7) << 16) + abase;
    int4 v[8];
#pragma unroll
    for (int kt = 0; kt < 8; ++kt) v[kt] = ld16(pA + kt * 32, esc);
    waitv0();
    u32 sm = 0;
#pragma unroll
    for (int kt = 0; kt < 8; ++kt) sm |= stale4(v[kt]) << kt;
    int spins = 0;
    while (sm) {
      if (!esc && ++spins >= 256) esc = true;
#pragma unroll
      for (int kt = 0; kt < 8; ++kt)
        if (sm & (1u << kt)) v[kt] = ld16(pA + kt * 32, esc);
      waitv0();
      sm = 0;
#pragma unroll
      for (int kt = 0; kt < 8; ++kt) sm |= stale4(v[kt]) << kt;
    }

    float xn = 0.f;
    if (t < 511) xn = io[iobase + (size_t)(t + 1) * 1024];
    if (t < 508) {  // reset buf[(t+4)&7]: holds h(t-4), consumed >=4 steps ago
      const size_t roff = ((size_t)((t + 4) & 7) << 16) + hword;
      stH(hhi + roff, 0xFFFFu);
      stH(hlo + roff, 0xFFFFu);
    }

    f32x4 acc[2] = {};
#pragma unroll
    for (int kt = 0; kt < 8; ++kt) {
      short8 a = *(short8*)&v[kt];
#pragma unroll
      for (int nt = 0; nt < 2; ++nt) {
        acc[nt] = MFMA16(a, bhf[kt][nt], acc[nt]);  // rows 0-7: hi*Whi, 8-15: lo*Whi
        acc[nt] = MFMA16(a, blf[kt][nt], acc[nt]);  // rows 0-7: hi*Wlo, 8-15: lo*Wlo
      }
    }

    float* rp = red + (t & 1) * 2112;
#pragma unroll
    for (int nt = 0; nt < 2; ++nt)
#pragma unroll
      for (int r = 0; r < 4; ++r)
        rp[wave * 528 + (q * 4 + r) * 33 + nt * 16 + mn] = acc[nt][r];
    __syncthreads();

    float s = 0.f;
#pragma unroll
    for (int w = 0; w < 4; ++w)
      s += rp[w * 528 + om * 33 + on] + rp[w * 528 + (om + 8) * 33 + on];
    float o = tanhf(s + xv);

    if (t < 511) {
      u16 hh = f2bf_rne(o);
      const size_t doff = ((size_t)((t + 1) & 7) << 16) + hword;
      stH(hhi + doff, hh);
      stH(hlo + doff, f2bf_rne(o - bf2f(hh)));
      __syncthreads();        // all 256 h(t+1) stores issued before flag
      if (tid == 0) stF(myflag, (u32)(t + 1));
    }
    io[iobase + (size_t)t * 1024] = o;
    xv = xn;
  }
}

// ---------------- phase 2 kernel ----------------
__global__ __launch_bounds__(256, 1) void rnn_steps(
    const u16* __restrict__ Wh, const u16* __restrict__ Wl, u16* hhi, u16* hlo,
    u32* cnt, u32* xccbuf, u32* flg, float* __restrict__ io) {
  extern __shared__ __align__(16) char smem[];
  u16* Whi = (u16*)smem;                 // [32][1032]  66048 B
  u16* Wlo = (u16*)(smem + 66048);       // [32][1032]  66048 B
  float* red = (float*)(smem + 132096);  // [2][4][16][33] 16896 B

  const int tid = threadIdx.x, wave = tid >> 6, lane = tid & 63;
  const int mn = lane & 15, q = lane >> 4;
  const int wgid = blockIdx.x;
  const int bg = wgid & 7, cg = wgid >> 3;
  const int c0 = cg * 32, b0 = bg * 8;
  u32* mycnt = cnt + bg * 64;

  // persistent W tile: 32 cols x 1024, hi+lo
  for (int it = tid; it < 32 * 128; it += 256) {
    int r = it >> 7, c = it & 127;
    *(short8*)&Whi[r * 1032 + c * 8] = *(const short8*)(Wh + (size_t)(c0 + r) * 1024 + c * 8);
    *(short8*)&Wlo[r * 1032 + c * 8] = *(const short8*)(Wl + (size_t)(c0 + r) * 1024 + c * 8);
  }

  // output ownership: 256 threads -> 8 batches x 32 cols, 1 col/thread
  const int om = tid >> 5, on = tid & 31;
  const size_t hword = (size_t)(b0 + om) * 1024 + (c0 + on);

  // sentinel-prefill my word in ALL 8 buffers (agent scope)
#pragma unroll
  for (int bb = 0; bb < 8; ++bb) {
    stH(hhi + ((size_t)bb << 16) + hword, 0xFFFFu);
    stH(hlo + ((size_t)bb << 16) + hword, 0xFFFFu);
  }

  // publish my XCD id (numeric hwreg 20 = XCC_ID, low 4 bits); per-bg startup
  // barrier; verify bg co-residency. Any mis-read is safe: false-negative -> agent
  // path; false-positive -> bounded-spin escalation.
  u32 xcc;
  asm volatile("s_getreg_b32 %0, hwreg(20, 0, 4)" : "=s"(xcc));
  if (tid == 0)
    __hip_atomic_store(xccbuf + wgid, xcc, __ATOMIC_RELAXED, SCOPE_AGENT);
  asm volatile("s_waitcnt vmcnt(0)" ::: "memory");
  __syncthreads();
  if (tid == 0) {
    __hip_atomic_fetch_add(mycnt, 1u, __ATOMIC_RELAXED, SCOPE_AGENT);
    while (__hip_atomic_load(mycnt, __ATOMIC_RELAXED, SCOPE_AGENT) < 32u)
      __builtin_amdgcn_s_sleep(1);
  }
  __syncthreads();

  u32 pv = __hip_atomic_load(xccbuf + bg + 8 * (lane & 31), __ATOMIC_RELAXED, SCOPE_AGENT);
  const bool fast = (__ballot(pv == xcc) == ~0ull);

  run_steps(hhi, hlo, io, Whi, Wlo, red, flg + bg * 32, flg + bg * 32 + cg, b0, c0,
            wave, mn, q, om, on, tid, lane, !fast);
}

// ---------------- host ----------------
extern "C" void kernel_launch(void* const* d_in, const int* in_sizes, int n_in, void* d_out,
                              int out_size, void* d_ws, size_t ws_size, hipStream_t stream) {
  (void)in_sizes; (void)n_in; (void)out_size; (void)ws_size;
  const float* x    = (const float*)d_in[0];
  const float* W_in = (const float*)d_in[1];
  const float* b_in = (const float*)d_in[2];
  const float* W_hh = (const float*)d_in[3];
  const float* bias = (const float*)d_in[4];
  float* out = (float*)d_out;
  char* ws = (char*)d_ws;

  u16* win_hi = (u16*)(ws);                     // 1 MB, dead after xin_gemm
  u16* win_lo = (u16*)(ws + (1u << 20));        // 1 MB, dead after xin_gemm
  u16* whh_hi = (u16*)(ws + (2u << 20));        // 2 MB
  u16* whh_lo = (u16*)(ws + (4u << 20));        // 2 MB
  float* bsum = (float*)(ws + (6u << 20));      // 4 KB
  u16* hhi    = (u16*)(ws);                     // aliases win_hi: 8 bufs x 64x1024 u16
  u16* hlo    = (u16*)(ws + (1u << 20));        // aliases win_lo
  u32* cnt    = (u32*)(ws + (6u << 20) + 65536);           // 8 x 256B counters
  u32* xcc    = (u32*)(ws + (6u << 20) + 65536 + 4096);    // 256 u32
  u32* flg    = (u32*)(ws + (6u << 20) + 65536 + 8192);    // flags[8][32], 128B/bg

  split_arr<<<dim3(524288 / 256), dim3(256), 0, stream>>>(W_in, win_hi, win_lo, 524288);
  split_arr<<<dim3(1048576 / 256), dim3(256), 0, stream>>>(W_hh, whh_hi, whh_lo, 1048576);
  bias_init<<<dim3(8), dim3(256), 0, stream>>>(b_in, bias, bsum, cnt, flg);

  xin_gemm<<<dim3(16, 512), dim3(256), 0, stream>>>(x, win_hi, win_lo, bsum, out);

  static const unsigned kSmem = 148992;  // 2*66048 + 16896
  (void)hipFuncSetAttribute((const void*)rnn_steps, hipFuncAttributeMaxDynamicSharedMemorySize,
                            (int)kSmem);
  void* args[8];
  args[0] = (void*)&whh_hi;
  args[1] = (void*)&whh_lo;
  args[2] = (void*)&hhi;
  args[3] = (void*)&hlo;
  args[4] = (void*)&cnt;
  args[5] = (void*)&xcc;
  args[6] = (void*)&flg;
  args[7] = (void*)&out;
  (void)hipLaunchCooperativeKernel((const void*)rnn_steps, dim3(256), dim3(256, 1, 1), args,
                                   kSmem, stream);
}